// Round 2
// baseline (411.078 us; speedup 1.0000x reference)
//
#include <hip/hip_runtime.h>
#include <hip/hip_cooperative_groups.h>

namespace cg = cooperative_groups;

// ---------------- problem constants ----------------
#define BATCH   4096
#define N_REL   500
#define D1      200
#define W_IN    400          // 2*D1
#define OC      32
#define FW      9
#define W_OUT   392          // W_IN - FW + 1
#define FC_LEN  12544        // OC * W_OUT
#define FC1_LEN 288          // OC * FW
#define EPS     1e-5f

#define OSPLIT  8            // o-dim split for wbig GEMV
#define OCH     50           // 400 / OSPLIT
#define WBLK    49           // 12544 / 256
#define GRID    512          // coop grid: 52 KB LDS -> 3 blk/CU -> cap 768

// ============================================================================
// Algebraic collapse (proven round 1): fc2_w is [1,400] -> entire post-conv
// network is affine into ONE scalar per example:
//   pre[b] = s0*( E[i1]·P[rel,0:200] + E[i2]·P[rel,200:400] ) + crel[rel]
//   out[b] = tanh(pre[b]) + bias
// This round: single cooperative launch (5 launches -> 1) to kill ~27 us/launch
// dispatch overhead; arithmetic identical.
// ============================================================================

struct Params {
    const int *e1i, *ri, *e2i;
    const float *E, *R;
    const float *g0, *b0, *m0p, *v0;
    const float *fc1w, *fc1b;
    const float *g1, *b1, *m1, *v1;
    const float *fcw, *fcb;
    const float *g2, *b2, *m2, *v2;
    const float *fc2w, *fc2b, *bias;
    float *KR, *wpart, *wbig, *c3part, *Ps, *crel, *out;
};

// ============ fused cooperative kernel ============
__global__ __launch_bounds__(256)
void fused_k(Params p)
{
    cg::grid_group grid = cg::this_grid();
    // phase B is the LDS high-water mark: 12544 + 288 + 256 floats = 52,352 B
    __shared__ __align__(16) float smem[13088];
    const int t  = threadIdx.x;
    const int bx = blockIdx.x;

    // ---------------- phase A: krel rows (500) + wbig o-split partials (392)
    for (int u = bx; u < N_REL + OSPLIT * WBLK; u += GRID) {
        if (u < N_REL) {
            // KR[u][i] = (R[u]·fc1w[i] + fc1b[i]) * inv1[i/9]
            float* rs = smem;
            if (t < D1) rs[t] = p.R[(size_t)u * D1 + t];
            __syncthreads();
            for (int i = t; i < FC1_LEN; i += 256) {
                const float4* wrow = (const float4*)(p.fc1w + (size_t)i * D1);
                float acc = p.fc1b[i];
                #pragma unroll 10
                for (int c = 0; c < D1 / 4; ++c) {
                    float4 wv = wrow[c];
                    acc += rs[c * 4 + 0] * wv.x + rs[c * 4 + 1] * wv.y
                         + rs[c * 4 + 2] * wv.z + rs[c * 4 + 3] * wv.w;
                }
                const int oc = i / FW;
                p.KR[(size_t)u * FC1_LEN + i] = acc * (p.g1[oc] * rsqrtf(p.v1[oc] + EPS));
            }
            __syncthreads();
        } else {
            // wpart[y][k] = sum_{o in slice y} fcw[o,k] * s2[o]*fc2w[o]
            const int v = u - N_REL;
            const int y = v / WBLK, kb = v - y * WBLK;
            const int o0 = y * OCH;
            float* wts = smem;
            if (t < OCH) {
                const int o = o0 + t;
                wts[t] = p.fc2w[o] * p.g2[o] * rsqrtf(p.v2[o] + EPS);
            }
            __syncthreads();
            const int k = kb * 256 + t;
            float acc = 0.f;
            #pragma unroll 10
            for (int i = 0; i < OCH; ++i)
                acc += p.fcw[(size_t)(o0 + i) * FC_LEN + k] * wts[i];
            p.wpart[y * FC_LEN + k] = acc;
            __syncthreads();
        }
    }
    grid.sync();

    // ---------------- phase A2: combine partials -> wbig; constants -> c3part
    if (bx < WBLK) {
        float* red = smem;
        const int k = bx * 256 + t;
        float w8 = 0.f;
        #pragma unroll
        for (int y = 0; y < OSPLIT; ++y) w8 += p.wpart[y * FC_LEN + k];
        p.wbig[k] = w8;
        const int oc = k / W_OUT;
        const float inv1 = p.g1[oc] * rsqrtf(p.v1[oc] + EPS);
        float pc = (p.b1[oc] - p.m1[oc] * inv1) * w8;
        if (bx == 0) {
            for (int o = t; o < W_IN; o += 256) {
                const float s2 = p.g2[o] * rsqrtf(p.v2[o] + EPS);
                pc += (p.b2[o] - p.m2[o] * s2 + p.fcb[o] * s2) * p.fc2w[o];
            }
            if (t == 0) pc += p.fc2b[0];
        }
        red[t] = pc;
        __syncthreads();
        #pragma unroll
        for (int s = 128; s > 0; s >>= 1) {
            if (t < s) red[t] += red[t + s];
            __syncthreads();
        }
        if (t == 0) p.c3part[bx] = red[0];
    }
    grid.sync();

    // ---------------- phase B: per-relation Ps row (s0 folded) + crel
    if (bx < N_REL) {
        float* wls = smem;              // 12544
        float* kfs = smem + FC_LEN;     // 288
        float* red = smem + FC_LEN + FC1_LEN;  // 256
        for (int i = t; i < FC_LEN / 4; i += 256)
            *(float4*)(wls + i * 4) = *(const float4*)(p.wbig + i * 4);
        for (int i = t; i < FC1_LEN; i += 256)
            kfs[i] = p.KR[(size_t)bx * FC1_LEN + i];
        __syncthreads();

        const float s0 = p.g0[0] * rsqrtf(p.v0[0] + EPS);
        const float t0 = p.b0[0] - p.m0p[0] * s0;

        float lsum = 0.f;
        for (int d = t; d < W_IN; d += 256) {
            const int jlo = (d > W_OUT - 1) ? d - (W_OUT - 1) : 0;
            const int jhi = (d < FW - 1) ? d : (FW - 1);
            float pp = 0.f;
            for (int oc = 0; oc < OC; ++oc) {
                const float* wb = wls + oc * W_OUT + d;
                const float* kk = kfs + oc * FW;
                for (int j = jlo; j <= jhi; ++j)
                    pp += kk[j] * wb[-j];
            }
            lsum += pp;
            p.Ps[(size_t)bx * W_IN + d] = s0 * pp;
        }
        red[t] = lsum;
        __syncthreads();
        #pragma unroll
        for (int s = 128; s > 0; s >>= 1) {
            if (t < s) red[t] += red[t + s];
            __syncthreads();
        }
        if (t == 0) {
            float cgs = 0.f;
            for (int i = 0; i < WBLK; ++i) cgs += p.c3part[i];
            p.crel[bx] = t0 * red[0] + cgs;
        }
    }
    grid.sync();

    // ---------------- phase C: gather + dot(400) + tanh, 2 examples/wave
    const int wave = t >> 6, lane = t & 63;
    for (int e = bx * 4 + wave; e < BATCH; e += GRID * 4) {
        const int i1 = p.e1i[e], i2 = p.e2i[e], rel = p.ri[e];
        const float* Pv = p.Ps + (size_t)rel * W_IN;
        const float* E1 = p.E + (size_t)i1 * D1;
        const float* E2 = p.E + (size_t)i2 * D1;
        float acc = 0.f;
        for (int d = lane; d < D1; d += 64)
            acc += E1[d] * Pv[d] + E2[d] * Pv[D1 + d];
        #pragma unroll
        for (int off = 32; off > 0; off >>= 1) acc += __shfl_down(acc, off);
        if (lane == 0) p.out[e] = tanhf(acc + p.crel[rel]) + p.bias[0];
    }
}

// ============================================================================
// Fallback path: proven round-1 5-kernel pipeline (used only if the
// cooperative launch is rejected).
// ============================================================================

__global__ __launch_bounds__(320)
void krel(const float* __restrict__ R, const float* __restrict__ fc1w,
          const float* __restrict__ fc1b,
          const float* __restrict__ g1, const float* __restrict__ v1,
          float* __restrict__ KR)
{
    __shared__ float rs[D1];
    const int rel = blockIdx.x;
    const int t = threadIdx.x;
    if (t < D1) rs[t] = R[(size_t)rel * D1 + t];
    __syncthreads();
    if (t < FC1_LEN) {
        const float4* wrow = (const float4*)(fc1w + (size_t)t * D1);
        float acc = fc1b[t];
        #pragma unroll 10
        for (int c = 0; c < D1 / 4; ++c) {
            float4 wv = wrow[c];
            acc += rs[c * 4 + 0] * wv.x + rs[c * 4 + 1] * wv.y
                 + rs[c * 4 + 2] * wv.z + rs[c * 4 + 3] * wv.w;
        }
        const int oc = t / FW;
        KR[(size_t)rel * FC1_LEN + t] = acc * (g1[oc] * rsqrtf(v1[oc] + EPS));
    }
}

__global__ __launch_bounds__(256)
void wpart_k(const float* __restrict__ fcw, const float* __restrict__ g2,
             const float* __restrict__ v2, const float* __restrict__ fc2w,
             float* __restrict__ wpart)
{
    __shared__ float wts[OCH];
    const int t = threadIdx.x;
    const int k = blockIdx.x * 256 + t;
    const int o0 = blockIdx.y * OCH;
    if (t < OCH) {
        const int o = o0 + t;
        wts[t] = fc2w[o] * g2[o] * rsqrtf(v2[o] + EPS);
    }
    __syncthreads();
    float acc = 0.f;
    #pragma unroll 10
    for (int i = 0; i < OCH; ++i)
        acc += fcw[(size_t)(o0 + i) * FC_LEN + k] * wts[i];
    wpart[blockIdx.y * FC_LEN + k] = acc;
}

__global__ __launch_bounds__(256)
void wsum_k(const float* __restrict__ wpart,
            const float* __restrict__ g1, const float* __restrict__ b1,
            const float* __restrict__ m1, const float* __restrict__ v1,
            const float* __restrict__ g2, const float* __restrict__ b2,
            const float* __restrict__ m2, const float* __restrict__ v2,
            const float* __restrict__ fcb, const float* __restrict__ fc2w,
            const float* __restrict__ fc2b,
            float* __restrict__ wbig, float* __restrict__ c3part)
{
    __shared__ float red[256];
    const int t = threadIdx.x;
    const int k = blockIdx.x * 256 + t;
    float w8 = 0.f;
    #pragma unroll
    for (int y = 0; y < OSPLIT; ++y) w8 += wpart[y * FC_LEN + k];
    wbig[k] = w8;
    const int oc = k / W_OUT;
    const float inv1 = g1[oc] * rsqrtf(v1[oc] + EPS);
    float pc = (b1[oc] - m1[oc] * inv1) * w8;
    if (blockIdx.x == 0) {
        for (int o = t; o < W_IN; o += 256) {
            const float s2 = g2[o] * rsqrtf(v2[o] + EPS);
            pc += (b2[o] - m2[o] * s2 + fcb[o] * s2) * fc2w[o];
        }
        if (t == 0) pc += fc2b[0];
    }
    red[t] = pc;
    __syncthreads();
    #pragma unroll
    for (int s = 128; s > 0; s >>= 1) {
        if (t < s) red[t] += red[t + s];
        __syncthreads();
    }
    if (t == 0) c3part[blockIdx.x] = red[0];
}

__global__ __launch_bounds__(256)
void prel_k(const float* __restrict__ KR, const float* __restrict__ wbig,
            const float* __restrict__ c3part,
            const float* __restrict__ g0, const float* __restrict__ b0,
            const float* __restrict__ m0p, const float* __restrict__ v0,
            float* __restrict__ Ps, float* __restrict__ crel)
{
    __shared__ __align__(16) float wls[FC_LEN];
    __shared__ float kfs[FC1_LEN];
    __shared__ float red[256];
    const int rel = blockIdx.x;
    const int t = threadIdx.x;

    for (int i = t; i < FC_LEN / 4; i += 256)
        *(float4*)(wls + i * 4) = *(const float4*)(wbig + i * 4);
    for (int i = t; i < FC1_LEN; i += 256)
        kfs[i] = KR[(size_t)rel * FC1_LEN + i];
    __syncthreads();

    const float s0 = g0[0] * rsqrtf(v0[0] + EPS);
    const float t0 = b0[0] - m0p[0] * s0;

    float lsum = 0.f;
    for (int d = t; d < W_IN; d += 256) {
        const int jlo = (d > W_OUT - 1) ? d - (W_OUT - 1) : 0;
        const int jhi = (d < FW - 1) ? d : (FW - 1);
        float pp = 0.f;
        for (int oc = 0; oc < OC; ++oc) {
            const float* wb = wls + oc * W_OUT + d;
            const float* kk = kfs + oc * FW;
            for (int j = jlo; j <= jhi; ++j)
                pp += kk[j] * wb[-j];
        }
        lsum += pp;
        Ps[(size_t)rel * W_IN + d] = s0 * pp;
    }
    red[t] = lsum;
    __syncthreads();
    #pragma unroll
    for (int s = 128; s > 0; s >>= 1) {
        if (t < s) red[t] += red[t + s];
        __syncthreads();
    }
    if (t == 0) {
        float cgs = 0.f;
        for (int i = 0; i < WBLK; ++i) cgs += c3part[i];
        crel[rel] = t0 * red[0] + cgs;
    }
}

__global__ __launch_bounds__(256)
void final_k(const int* __restrict__ e1i, const int* __restrict__ ri,
             const int* __restrict__ e2i,
             const float* __restrict__ E, const float* __restrict__ Ps,
             const float* __restrict__ crel, const float* __restrict__ bias,
             float* __restrict__ out)
{
    const int wave = threadIdx.x >> 6, lane = threadIdx.x & 63;
    const int e = blockIdx.x * 4 + wave;
    const int i1 = e1i[e], i2 = e2i[e], rel = ri[e];
    const float* P  = Ps + (size_t)rel * W_IN;
    const float* E1 = E + (size_t)i1 * D1;
    const float* E2 = E + (size_t)i2 * D1;
    float acc = 0.f;
    for (int d = lane; d < D1; d += 64) acc += E1[d] * P[d];
    for (int d = lane; d < D1; d += 64) acc += E2[d] * P[D1 + d];
    #pragma unroll
    for (int off = 32; off > 0; off >>= 1) acc += __shfl_down(acc, off);
    if (lane == 0) out[e] = tanhf(acc + crel[rel]) + bias[0];
}

extern "C" void kernel_launch(void* const* d_in, const int* in_sizes, int n_in,
                              void* d_out, int out_size, void* d_ws, size_t ws_size,
                              hipStream_t stream)
{
    const int*   e1i  = (const int*)d_in[0];
    const int*   ri   = (const int*)d_in[1];
    const int*   e2i  = (const int*)d_in[2];
    const float* E    = (const float*)d_in[3];
    const float* R    = (const float*)d_in[4];
    const float* g0   = (const float*)d_in[5];
    const float* b0   = (const float*)d_in[6];
    const float* m0p  = (const float*)d_in[7];
    const float* v0   = (const float*)d_in[8];
    const float* fc1w = (const float*)d_in[9];
    const float* fc1b = (const float*)d_in[10];
    const float* g1   = (const float*)d_in[11];
    const float* b1   = (const float*)d_in[12];
    const float* m1   = (const float*)d_in[13];
    const float* v1   = (const float*)d_in[14];
    const float* fcw  = (const float*)d_in[15];
    const float* fcb  = (const float*)d_in[16];
    const float* g2   = (const float*)d_in[17];
    const float* b2   = (const float*)d_in[18];
    const float* m2   = (const float*)d_in[19];
    const float* v2   = (const float*)d_in[20];
    const float* fc2w = (const float*)d_in[21];
    const float* fc2b = (const float*)d_in[22];
    const float* bias = (const float*)d_in[23];

    // workspace layout (all 16B-aligned, ~1.8 MB total)
    char* ws = (char*)d_ws;
    float* KR     = (float*)(ws + 0);              //  576000 B
    float* wpart  = (float*)(ws + 576000);         //  401408 B
    float* wbig   = (float*)(ws + 977408);         //   50176 B
    float* c3part = (float*)(ws + 1027584);        //     196 B
    float* Ps     = (float*)(ws + 1027840);        //  800000 B
    float* crel   = (float*)(ws + 1827840);        //    2000 B
    (void)ws_size; (void)in_sizes; (void)n_in; (void)out_size;

    Params prm = { e1i, ri, e2i, E, R, g0, b0, m0p, v0, fc1w, fc1b,
                   g1, b1, m1, v1, fcw, fcb, g2, b2, m2, v2,
                   fc2w, fc2b, bias,
                   KR, wpart, wbig, c3part, Ps, crel, (float*)d_out };
    void* args[] = { &prm };

    hipError_t err = hipLaunchCooperativeKernel((const void*)fused_k,
                                                dim3(GRID), dim3(256),
                                                args, 0, stream);
    if (err != hipSuccess) {
        (void)hipGetLastError();   // clear sticky error, use proven 5-kernel path
        krel<<<N_REL, 320, 0, stream>>>(R, fc1w, fc1b, g1, v1, KR);
        wpart_k<<<dim3(WBLK, OSPLIT), 256, 0, stream>>>(fcw, g2, v2, fc2w, wpart);
        wsum_k<<<WBLK, 256, 0, stream>>>(wpart, g1, b1, m1, v1, g2, b2, m2, v2,
                                         fcb, fc2w, fc2b, wbig, c3part);
        prel_k<<<N_REL, 256, 0, stream>>>(KR, wbig, c3part, g0, b0, m0p, v0, Ps, crel);
        final_k<<<BATCH / 4, 256, 0, stream>>>(e1i, ri, e2i, E, Ps, crel, bias,
                                               (float*)d_out);
    }
}

// Round 4
// 237.045 us; speedup vs baseline: 1.7342x; 1.7342x over previous
//
#include <hip/hip_runtime.h>

// ---------------- problem constants ----------------
#define BATCH   4096
#define N_REL   500
#define D1      200
#define W_IN    400          // 2*D1
#define OC      32
#define FW      9
#define W_OUT   392          // W_IN - FW + 1
#define FC_LEN  12544        // OC * W_OUT
#define FC1_LEN 288          // OC * FW
#define EPS     1e-5f

#define OSPLIT  8            // o-dim split for wbig GEMV
#define OCH     50           // 400 / OSPLIT
#define WBLK    49           // 12544 / 256
#define CHUNK   512          // example-scan chunk in prelfin

// ============================================================================
// Algebraic collapse (proven round 1): fc2_w is [1,400] -> entire post-conv
// network is affine into ONE scalar per example:
//   pre[b] = s0*( E[i1]·P[rel,0:200] + E[i2]·P[rel,200:400] ) + crel[rel]
//   out[b] = tanh(pre[b]) + bias
// Round 2 lesson: cooperative grid.sync costs ~70us each at this occupancy ->
// reverted. Round 3 failed on container acquisition (infra), not the kernel;
// this is a clean resubmit of the 3-launch structure:
//   launch 1: krel rows + wbig o-slice partials (independent, block-split)
//   launch 2: combine partials -> wbig + constant reduction
//   launch 3: per-relation P-row in LDS + finish that relation's examples
// ============================================================================

// ============ kernel AB: krel rows (blocks 0..499) + wbig partials (500..891)
__global__ __launch_bounds__(256)
void ab_k(const float* __restrict__ R, const float* __restrict__ fc1w,
          const float* __restrict__ fc1b,
          const float* __restrict__ g1, const float* __restrict__ v1,
          const float* __restrict__ fcw, const float* __restrict__ g2,
          const float* __restrict__ v2, const float* __restrict__ fc2w,
          float* __restrict__ KR, float* __restrict__ wpart)
{
    __shared__ float sm[D1];
    const int bx = blockIdx.x;
    const int t  = threadIdx.x;

    if (bx < N_REL) {
        // KR[bx][i] = (R[bx]·fc1w[i] + fc1b[i]) * inv1[i/9]
        if (t < D1) sm[t] = R[(size_t)bx * D1 + t];
        __syncthreads();
        for (int i = t; i < FC1_LEN; i += 256) {
            const float4* wrow = (const float4*)(fc1w + (size_t)i * D1);
            float acc = fc1b[i];
            #pragma unroll 10
            for (int c = 0; c < D1 / 4; ++c) {
                float4 wv = wrow[c];
                acc += sm[c * 4 + 0] * wv.x + sm[c * 4 + 1] * wv.y
                     + sm[c * 4 + 2] * wv.z + sm[c * 4 + 3] * wv.w;
            }
            const int oc = i / FW;
            KR[(size_t)bx * FC1_LEN + i] = acc * (g1[oc] * rsqrtf(v1[oc] + EPS));
        }
    } else {
        // wpart[y][k] = sum_{o in slice y} fcw[o,k] * s2[o]*fc2w[o]
        const int v = bx - N_REL;          // 0..391
        const int y = v / WBLK, kb = v - y * WBLK;
        const int o0 = y * OCH;
        if (t < OCH) {
            const int o = o0 + t;
            sm[t] = fc2w[o] * g2[o] * rsqrtf(v2[o] + EPS);
        }
        __syncthreads();
        const int k = kb * 256 + t;
        float acc = 0.f;
        #pragma unroll 10
        for (int i = 0; i < OCH; ++i)
            acc += fcw[(size_t)(o0 + i) * FC_LEN + k] * sm[i];
        wpart[y * FC_LEN + k] = acc;
    }
}

// ============ kernel W2: combine partials -> wbig; constant partials ========
__global__ __launch_bounds__(256)
void wsum_k(const float* __restrict__ wpart,
            const float* __restrict__ g1, const float* __restrict__ b1,
            const float* __restrict__ m1, const float* __restrict__ v1,
            const float* __restrict__ g2, const float* __restrict__ b2,
            const float* __restrict__ m2, const float* __restrict__ v2,
            const float* __restrict__ fcb, const float* __restrict__ fc2w,
            const float* __restrict__ fc2b,
            float* __restrict__ wbig, float* __restrict__ c3part)
{
    __shared__ float red[256];
    const int t = threadIdx.x;
    const int k = blockIdx.x * 256 + t;
    float w8 = 0.f;
    #pragma unroll
    for (int y = 0; y < OSPLIT; ++y) w8 += wpart[y * FC_LEN + k];
    wbig[k] = w8;
    const int oc = k / W_OUT;
    const float inv1 = g1[oc] * rsqrtf(v1[oc] + EPS);
    float pc = (b1[oc] - m1[oc] * inv1) * w8;
    if (blockIdx.x == 0) {
        for (int o = t; o < W_IN; o += 256) {
            const float s2 = g2[o] * rsqrtf(v2[o] + EPS);
            pc += (b2[o] - m2[o] * s2 + fcb[o] * s2) * fc2w[o];
        }
        if (t == 0) pc += fc2b[0];
    }
    red[t] = pc;
    __syncthreads();
    #pragma unroll
    for (int s = 128; s > 0; s >>= 1) {
        if (t < s) red[t] += red[t + s];
        __syncthreads();
    }
    if (t == 0) c3part[blockIdx.x] = red[0];
}

// ============ kernel PF: per-relation Ps row in LDS + finish its examples ===
// block rel: prow[d] = s0 * sum_{oc,j} KR[rel,oc*9+j]*wbig[oc*392+d-j]
//            crelS   = t0 * sum_d P + sum(c3part)
//            for each e with ri[e]==rel: out[e] = tanh(E-dot + crelS) + bias
__global__ __launch_bounds__(256)
void prelfin_k(const int* __restrict__ e1i, const int* __restrict__ ri,
               const int* __restrict__ e2i, const float* __restrict__ E,
               const float* __restrict__ KR, const float* __restrict__ wbig,
               const float* __restrict__ c3part,
               const float* __restrict__ g0, const float* __restrict__ b0,
               const float* __restrict__ m0p, const float* __restrict__ v0,
               const float* __restrict__ bias,
               float* __restrict__ out)
{
    __shared__ __align__(16) float wls[FC_LEN];    // 50176 B
    __shared__ float kfs[FC1_LEN];                 //  1152 B
    __shared__ float red[256];                     //  1024 B
    __shared__ float prow[W_IN];                   //  1600 B
    __shared__ float crelS;
    __shared__ int   list[CHUNK];                  //  2048 B
    __shared__ int   cnt;

    const int rel = blockIdx.x;
    const int t = threadIdx.x;
    const int wave = t >> 6, lane = t & 63;

    for (int i = t; i < FC_LEN / 4; i += 256)
        *(float4*)(wls + i * 4) = *(const float4*)(wbig + i * 4);
    for (int i = t; i < FC1_LEN; i += 256)
        kfs[i] = KR[(size_t)rel * FC1_LEN + i];
    __syncthreads();

    const float s0 = g0[0] * rsqrtf(v0[0] + EPS);
    const float t0 = b0[0] - m0p[0] * s0;

    float lsum = 0.f;
    for (int d = t; d < W_IN; d += 256) {
        const int jlo = (d > W_OUT - 1) ? d - (W_OUT - 1) : 0;
        const int jhi = (d < FW - 1) ? d : (FW - 1);
        float pp = 0.f;
        for (int oc = 0; oc < OC; ++oc) {
            const float* wb = wls + oc * W_OUT + d;
            const float* kk = kfs + oc * FW;
            for (int j = jlo; j <= jhi; ++j)
                pp += kk[j] * wb[-j];
        }
        lsum += pp;
        prow[d] = s0 * pp;
    }
    red[t] = lsum;
    __syncthreads();
    #pragma unroll
    for (int s = 128; s > 0; s >>= 1) {
        if (t < s) red[t] += red[t + s];
        __syncthreads();
    }
    if (t == 0) {
        float cgs = 0.f;
        for (int i = 0; i < WBLK; ++i) cgs += c3part[i];
        crelS = t0 * red[0] + cgs;
    }
    __syncthreads();

    const float cr = crelS;
    const float bi = bias[0];

    // scan examples in chunks; waves finish matches from LDS prow
    for (int c0 = 0; c0 < BATCH; c0 += CHUNK) {
        if (t == 0) cnt = 0;
        __syncthreads();
        for (int e = c0 + t; e < c0 + CHUNK; e += 256)
            if (ri[e] == rel) {
                const int idx = atomicAdd(&cnt, 1);
                list[idx] = e;
            }
        __syncthreads();
        const int n = cnt;
        for (int q = wave; q < n; q += 4) {
            const int e = list[q];
            const float* E1 = E + (size_t)e1i[e] * D1;
            const float* E2 = E + (size_t)e2i[e] * D1;
            float acc = 0.f;
            for (int d = lane; d < D1; d += 64) acc += E1[d] * prow[d];
            for (int d = lane; d < D1; d += 64) acc += E2[d] * prow[D1 + d];
            #pragma unroll
            for (int off = 32; off > 0; off >>= 1) acc += __shfl_down(acc, off);
            if (lane == 0) out[e] = tanhf(acc + cr) + bi;
        }
        __syncthreads();
    }
}

extern "C" void kernel_launch(void* const* d_in, const int* in_sizes, int n_in,
                              void* d_out, int out_size, void* d_ws, size_t ws_size,
                              hipStream_t stream)
{
    const int*   e1i  = (const int*)d_in[0];
    const int*   ri   = (const int*)d_in[1];
    const int*   e2i  = (const int*)d_in[2];
    const float* E    = (const float*)d_in[3];
    const float* R    = (const float*)d_in[4];
    const float* g0   = (const float*)d_in[5];
    const float* b0   = (const float*)d_in[6];
    const float* m0p  = (const float*)d_in[7];
    const float* v0   = (const float*)d_in[8];
    const float* fc1w = (const float*)d_in[9];
    const float* fc1b = (const float*)d_in[10];
    const float* g1   = (const float*)d_in[11];
    const float* b1   = (const float*)d_in[12];
    const float* m1   = (const float*)d_in[13];
    const float* v1   = (const float*)d_in[14];
    const float* fcw  = (const float*)d_in[15];
    const float* fcb  = (const float*)d_in[16];
    const float* g2   = (const float*)d_in[17];
    const float* b2   = (const float*)d_in[18];
    const float* m2   = (const float*)d_in[19];
    const float* v2   = (const float*)d_in[20];
    const float* fc2w = (const float*)d_in[21];
    const float* fc2b = (const float*)d_in[22];
    const float* bias = (const float*)d_in[23];

    // workspace layout (16B-aligned, ~1.03 MB total)
    char* ws = (char*)d_ws;
    float* KR     = (float*)(ws + 0);              //  576000 B
    float* wpart  = (float*)(ws + 576000);         //  401408 B
    float* wbig   = (float*)(ws + 977408);         //   50176 B
    float* c3part = (float*)(ws + 1027584);        //     196 B
    (void)ws_size; (void)in_sizes; (void)n_in; (void)out_size;

    ab_k<<<N_REL + OSPLIT * WBLK, 256, 0, stream>>>(R, fc1w, fc1b, g1, v1,
                                                    fcw, g2, v2, fc2w, KR, wpart);
    wsum_k<<<WBLK, 256, 0, stream>>>(wpart, g1, b1, m1, v1, g2, b2, m2, v2,
                                     fcb, fc2w, fc2b, wbig, c3part);
    prelfin_k<<<N_REL, 256, 0, stream>>>(e1i, ri, e2i, E, KR, wbig, c3part,
                                         g0, b0, m0p, v0, bias, (float*)d_out);
}

// Round 5
// 192.592 us; speedup vs baseline: 2.1345x; 1.2308x over previous
//
#include <hip/hip_runtime.h>

// ---------------- problem constants ----------------
#define BATCH   4096
#define N_REL   500
#define D1      200
#define W_IN    400          // 2*D1
#define OC      32
#define FW      9
#define W_OUT   392          // W_IN - FW + 1
#define FC_LEN  12544        // OC * W_OUT
#define FC1_LEN 288          // OC * FW
#define EPS     1e-5f

#define OSPLIT  8            // o-dim split for wbig GEMV
#define OCH     50           // 400 / OSPLIT
#define WBLK    49           // 12544 / 256
#define WPADL   408          // padded oc-row length (8 left pad + 392 + 8 right)

// ============================================================================
// Algebraic collapse (proven round 1): fc2_w is [1,400] -> entire post-conv
// network is affine into ONE scalar per example:
//   pre[b] = s0*( E[i1]·P[rel,0:200] + E[i2]·P[rel,200:400] ) + crel[rel]
//   out[b] = tanh(pre[b]) + bias
// Round 4 post-mortem: merging final into prel cost 67us -- conv loop was
// LDS-instruction-bound (scalar ds_read_b32, variable tap bounds) and the
// appended example scan serialized HBM gathers at 17% occupancy. This round:
// split prel/final again (4 launches) + register-stencil conv with zero-padded
// rows -> unconditional taps, ds_read_b128 only (~9x fewer LDS instrs).
// ============================================================================

// ============ kernel AB: krel rows (blocks 0..499) + wbig partials (500..891)
__global__ __launch_bounds__(256)
void ab_k(const float* __restrict__ R, const float* __restrict__ fc1w,
          const float* __restrict__ fc1b,
          const float* __restrict__ g1, const float* __restrict__ v1,
          const float* __restrict__ fcw, const float* __restrict__ g2,
          const float* __restrict__ v2, const float* __restrict__ fc2w,
          float* __restrict__ KR, float* __restrict__ wpart)
{
    __shared__ float sm[D1];
    const int bx = blockIdx.x;
    const int t  = threadIdx.x;

    if (bx < N_REL) {
        // KR[bx][i] = (R[bx]·fc1w[i] + fc1b[i]) * inv1[i/9]
        if (t < D1) sm[t] = R[(size_t)bx * D1 + t];
        __syncthreads();
        for (int i = t; i < FC1_LEN; i += 256) {
            const float4* wrow = (const float4*)(fc1w + (size_t)i * D1);
            float acc = fc1b[i];
            #pragma unroll 10
            for (int c = 0; c < D1 / 4; ++c) {
                float4 wv = wrow[c];
                acc += sm[c * 4 + 0] * wv.x + sm[c * 4 + 1] * wv.y
                     + sm[c * 4 + 2] * wv.z + sm[c * 4 + 3] * wv.w;
            }
            const int oc = i / FW;
            KR[(size_t)bx * FC1_LEN + i] = acc * (g1[oc] * rsqrtf(v1[oc] + EPS));
        }
    } else {
        // wpart[y][k] = sum_{o in slice y} fcw[o,k] * s2[o]*fc2w[o]
        const int v = bx - N_REL;          // 0..391
        const int y = v / WBLK, kb = v - y * WBLK;
        const int o0 = y * OCH;
        if (t < OCH) {
            const int o = o0 + t;
            sm[t] = fc2w[o] * g2[o] * rsqrtf(v2[o] + EPS);
        }
        __syncthreads();
        const int k = kb * 256 + t;
        float acc = 0.f;
        #pragma unroll 10
        for (int i = 0; i < OCH; ++i)
            acc += fcw[(size_t)(o0 + i) * FC_LEN + k] * sm[i];
        wpart[y * FC_LEN + k] = acc;
    }
}

// ============ kernel W2: combine partials -> wbig; constant partials ========
__global__ __launch_bounds__(256)
void wsum_k(const float* __restrict__ wpart,
            const float* __restrict__ g1, const float* __restrict__ b1,
            const float* __restrict__ m1, const float* __restrict__ v1,
            const float* __restrict__ g2, const float* __restrict__ b2,
            const float* __restrict__ m2, const float* __restrict__ v2,
            const float* __restrict__ fcb, const float* __restrict__ fc2w,
            const float* __restrict__ fc2b,
            float* __restrict__ wbig, float* __restrict__ c3part)
{
    __shared__ float red[256];
    const int t = threadIdx.x;
    const int k = blockIdx.x * 256 + t;
    float w8 = 0.f;
    #pragma unroll
    for (int y = 0; y < OSPLIT; ++y) w8 += wpart[y * FC_LEN + k];
    wbig[k] = w8;
    const int oc = k / W_OUT;
    const float inv1 = g1[oc] * rsqrtf(v1[oc] + EPS);
    float pc = (b1[oc] - m1[oc] * inv1) * w8;
    if (blockIdx.x == 0) {
        for (int o = t; o < W_IN; o += 256) {
            const float s2 = g2[o] * rsqrtf(v2[o] + EPS);
            pc += (b2[o] - m2[o] * s2 + fcb[o] * s2) * fc2w[o];
        }
        if (t == 0) pc += fc2b[0];
    }
    red[t] = pc;
    __syncthreads();
    #pragma unroll
    for (int s = 128; s > 0; s >>= 1) {
        if (t < s) red[t] += red[t + s];
        __syncthreads();
    }
    if (t == 0) c3part[blockIdx.x] = red[0];
}

// ============ kernel P: per-relation Ps row, register-stencil conv ==========
// wpad[oc][x] = wbig[oc*392 + x - 8] for 8<=x<400, else 0  (taps unconditional)
// thread u<100 owns d = 4u..4u+3:
//   P[d] = sum_oc sum_{j=0..8} kfp[oc][j] * wpad[oc][d+8-j]
// (padded taps contribute exact +0.0 -> bitwise identical to bounded loop)
__global__ __launch_bounds__(256)
void prel_k(const float* __restrict__ KR, const float* __restrict__ wbig,
            const float* __restrict__ c3part,
            const float* __restrict__ g0, const float* __restrict__ b0,
            const float* __restrict__ m0p, const float* __restrict__ v0,
            float* __restrict__ Ps, float* __restrict__ crel)
{
    __shared__ __align__(16) float wpad[OC * WPADL];   // 52224 B
    __shared__ __align__(16) float kfp[OC * 12];       //  1536 B
    __shared__ float red[256];                         //  1024 B
    const int rel = blockIdx.x;
    const int t = threadIdx.x;

    // zero the 16 pad floats per oc (x in [0,8) and [400,408))
    for (int u = t; u < OC * 16; u += 256) {
        const int oc = u >> 4, x = u & 15;
        wpad[oc * WPADL + (x < 8 ? x : 392 + x)] = 0.f;
    }
    // interior: 98 float4 per oc, both sides 16B-aligned
    for (int u = t; u < OC * 98; u += 256) {
        const int oc = u / 98, c = u - oc * 98;
        *(float4*)(wpad + oc * WPADL + 8 + c * 4) =
            *(const float4*)(wbig + oc * W_OUT + c * 4);
    }
    // filter taps padded to 12/oc
    for (int u = t; u < OC * 12; u += 256) {
        const int oc = u / 12, j = u - oc * 12;
        kfp[u] = (j < FW) ? KR[(size_t)rel * FC1_LEN + oc * FW + j] : 0.f;
    }
    __syncthreads();

    const float s0 = g0[0] * rsqrtf(v0[0] + EPS);
    const float t0 = b0[0] - m0p[0] * s0;

    float lsum = 0.f;
    if (t < 100) {
        const int d0 = t * 4;
        float a0 = 0.f, a1 = 0.f, a2 = 0.f, a3 = 0.f;
        for (int oc = 0; oc < OC; ++oc) {
            const float* wb = wpad + oc * WPADL + d0;
            float4 wA = *(const float4*)(wb);
            float4 wB = *(const float4*)(wb + 4);
            float4 wC = *(const float4*)(wb + 8);
            const float w[12] = {wA.x, wA.y, wA.z, wA.w,
                                 wB.x, wB.y, wB.z, wB.w,
                                 wC.x, wC.y, wC.z, wC.w};
            const float* kp = kfp + oc * 12;
            float4 k0 = *(const float4*)(kp);
            float4 k1 = *(const float4*)(kp + 4);
            float4 k2 = *(const float4*)(kp + 8);
            const float k[12] = {k0.x, k0.y, k0.z, k0.w,
                                 k1.x, k1.y, k1.z, k1.w,
                                 k2.x, k2.y, k2.z, k2.w};
            #pragma unroll
            for (int j = 0; j < FW; ++j) {
                const float kj = k[j];
                a0 += kj * w[8 - j];
                a1 += kj * w[9 - j];
                a2 += kj * w[10 - j];
                a3 += kj * w[11 - j];
            }
        }
        lsum = a0 + a1 + a2 + a3;
        float4 o = {s0 * a0, s0 * a1, s0 * a2, s0 * a3};
        *(float4*)(Ps + (size_t)rel * W_IN + d0) = o;   // 16B aligned
    }
    red[t] = lsum;
    __syncthreads();
    #pragma unroll
    for (int s = 128; s > 0; s >>= 1) {
        if (t < s) red[t] += red[t + s];
        __syncthreads();
    }
    if (t == 0) {
        float cgs = 0.f;
        for (int i = 0; i < WBLK; ++i) cgs += c3part[i];
        crel[rel] = t0 * red[0] + cgs;
    }
}

// ============ kernel F: per-example gather + dot(400) + tanh ================
__global__ __launch_bounds__(256)
void final_k(const int* __restrict__ e1i, const int* __restrict__ ri,
             const int* __restrict__ e2i,
             const float* __restrict__ E, const float* __restrict__ Ps,
             const float* __restrict__ crel, const float* __restrict__ bias,
             float* __restrict__ out)
{
    const int wave = threadIdx.x >> 6, lane = threadIdx.x & 63;
    const int e = blockIdx.x * 4 + wave;
    const int i1 = e1i[e], i2 = e2i[e], rel = ri[e];
    const float* P  = Ps + (size_t)rel * W_IN;
    const float* E1 = E + (size_t)i1 * D1;
    const float* E2 = E + (size_t)i2 * D1;
    float acc = 0.f;
    for (int d = lane; d < D1; d += 64) acc += E1[d] * P[d];
    for (int d = lane; d < D1; d += 64) acc += E2[d] * P[D1 + d];
    #pragma unroll
    for (int off = 32; off > 0; off >>= 1) acc += __shfl_down(acc, off);
    if (lane == 0) out[e] = tanhf(acc + crel[rel]) + bias[0];
}

extern "C" void kernel_launch(void* const* d_in, const int* in_sizes, int n_in,
                              void* d_out, int out_size, void* d_ws, size_t ws_size,
                              hipStream_t stream)
{
    const int*   e1i  = (const int*)d_in[0];
    const int*   ri   = (const int*)d_in[1];
    const int*   e2i  = (const int*)d_in[2];
    const float* E    = (const float*)d_in[3];
    const float* R    = (const float*)d_in[4];
    const float* g0   = (const float*)d_in[5];
    const float* b0   = (const float*)d_in[6];
    const float* m0p  = (const float*)d_in[7];
    const float* v0   = (const float*)d_in[8];
    const float* fc1w = (const float*)d_in[9];
    const float* fc1b = (const float*)d_in[10];
    const float* g1   = (const float*)d_in[11];
    const float* b1   = (const float*)d_in[12];
    const float* m1   = (const float*)d_in[13];
    const float* v1   = (const float*)d_in[14];
    const float* fcw  = (const float*)d_in[15];
    const float* fcb  = (const float*)d_in[16];
    const float* g2   = (const float*)d_in[17];
    const float* b2   = (const float*)d_in[18];
    const float* m2   = (const float*)d_in[19];
    const float* v2   = (const float*)d_in[20];
    const float* fc2w = (const float*)d_in[21];
    const float* fc2b = (const float*)d_in[22];
    const float* bias = (const float*)d_in[23];

    // workspace layout (16B-aligned, ~1.83 MB total)
    char* ws = (char*)d_ws;
    float* KR     = (float*)(ws + 0);              //  576000 B
    float* wpart  = (float*)(ws + 576000);         //  401408 B
    float* wbig   = (float*)(ws + 977408);         //   50176 B
    float* c3part = (float*)(ws + 1027584);        //     196 B
    float* Ps     = (float*)(ws + 1027840);        //  800000 B
    float* crel   = (float*)(ws + 1827840);        //    2000 B
    (void)ws_size; (void)in_sizes; (void)n_in; (void)out_size;

    ab_k<<<N_REL + OSPLIT * WBLK, 256, 0, stream>>>(R, fc1w, fc1b, g1, v1,
                                                    fcw, g2, v2, fc2w, KR, wpart);
    wsum_k<<<WBLK, 256, 0, stream>>>(wpart, g1, b1, m1, v1, g2, b2, m2, v2,
                                     fcb, fc2w, fc2b, wbig, c3part);
    prel_k<<<N_REL, 256, 0, stream>>>(KR, wbig, c3part, g0, b0, m0p, v0, Ps, crel);
    final_k<<<BATCH / 4, 256, 0, stream>>>(e1i, ri, e2i, E, Ps, crel, bias,
                                           (float*)d_out);
}